// Round 10
// baseline (290.589 us; speedup 1.0000x reference)
//
#include <hip/hip_runtime.h>
#include <hip/hip_bf16.h>
#include <type_traits>

#define NV 23
#define NTOT 16384
#define FLAT (NV * 256)    // 5888 floats per slab
#define FLAT4 (FLAT / 4)   // 1472
#define CH 184             // f32x4 per wave (1472/8)
#define NS 3               // reg slots per chunk (64+64+56)
#define SLAB 23552         // slab bytes

// stats: X'[4]@0 (65536) | raw[4]@65536 (94208) -> 159744; grid 512 x NB0=32
#define NB0 32
#define ROFF0 65536
// write: X'[2]@0 (32768) | raw[2]@32768 (47104) | O@79872 (23552) -> 103424; grid 512 x NB1=32
#define NB1 32
#define ROFF1 32768
#define OOFF1 79872

typedef short s16x8 __attribute__((ext_vector_type(8)));
typedef float f32x4 __attribute__((ext_vector_type(4)));
typedef unsigned u32x4 __attribute__((ext_vector_type(4)));

template <int V> using Ic = std::integral_constant<int, V>;

// x/23 for 0 <= x < 61681
__device__ __forceinline__ int divNV(int x) { return (int)(((unsigned)x * 45591u) >> 20); }
// f32 -> bf16 bits, RNE
__device__ __forceinline__ unsigned f2bf(float f) {
  unsigned u = __float_as_uint(f);
  u += 0x7fffu + ((u >> 16) & 1u);
  return u >> 16;
}
// X' column swizzle (16-B granules): 6 distinct groups for w-strides of 4
// (form writes conflict-free), read rows pair-wise 2-way (free).
__device__ __forceinline__ int fsw(int w) { return ((w + (w >> 3)) * 3) & 7; }

// async global->LDS DMA, 16B per lane (lds dest wave-uniform, HW adds lane*16)
__device__ __forceinline__ void gl_lds16(const void* g, void* l) {
  __builtin_amdgcn_global_load_lds(
      (const __attribute__((address_space(1))) unsigned*)(unsigned long long)(uintptr_t)g,
      (__attribute__((address_space(3))) unsigned*)(unsigned)(uintptr_t)l, 16, 0, 0);
}

// ws layout (bytes): Wt@0 (131072) | tab@131072 (23552) | sum@154624 | ssq@178176
//                    | An2@201728 | Bn2@225280 -> 248832 total
__global__ void k_prep(const float* __restrict__ W, const float* __restrict__ mask,
                       short* __restrict__ Wt, unsigned* __restrict__ tab,
                       float* __restrict__ sums) {
  int idx = blockIdx.x * 256 + threadIdx.x;  // grid 256 -> 65536
  int d = idx >> 8, c = idx & 255;
  Wt[idx] = (short)f2bf(W[c * 256 + d]);     // W^T in bf16: Wt[d][c]
  if (idx < FLAT) {
    // p = idx = c*23 + v ; w = (v - c) mod 23 ; swizzled LDS byte offset
    int cc = divNV(idx);
    int v = idx - NV * cc;
    int cm = cc - NV * divNV(cc);
    int w = v - cm; w += (w >> 31) & NV;
    unsigned off = (unsigned)((w << 9) + ((cc << 1) ^ (fsw(w) << 4)));
    tab[idx] = (f2bf(tanhf(mask[(w << 8) + cc]) + 1.0f) << 16) | off;
  }
  if (idx < 2 * FLAT) sums[idx] = 0.0f;      // zero sum+ssq
}

__global__ void k_finalize(const float* __restrict__ sum, const float* __restrict__ ssq,
                           const float* __restrict__ bnw, const float* __restrict__ bnb,
                           float* __restrict__ An2, float* __restrict__ Bn2) {
  int idx = blockIdx.x * 256 + threadIdx.x;  // (w,d) feature in y-space
  if (idx >= FLAT) return;
  int w = idx >> 8, d = idx & 255;
  float mean = sum[idx] * (1.0f / NTOT);
  float var  = ssq[idx] * (1.0f / NTOT) - mean * mean;
  float inv  = rsqrtf(var + 1e-5f);
  int i = w + d; i -= NV * divNV(i);         // out-shift row i = (w+d) % 23
  float a = inv * bnw[i * 256 + d];
  An2[d * NV + i] = a;                       // j-indexed (flat out order)
  Bn2[d * NV + i] = bnb[i * 256 + d] - mean * a;
}

// WRITE=0: stats (2 slabs/phase, X'[4]+raw[4]).  WRITE=1: output pass
// (1 slab/phase, X'[2]+raw[2]+O; residual stashed in regs during form).
// Phase order (R10): stage -> MFMA-consume -> epilogue -> form(next).
// mstep's ds_reads issue first (small lgkm counts feed MFMA); form's
// scattered writes go last, draining into the barrier that needed them.
template <int WRITE>
__global__ __launch_bounds__(512) void k_gemm(
    const float* __restrict__ x0, const short* __restrict__ Wt,
    const unsigned* __restrict__ tab, float* __restrict__ sum, float* __restrict__ ssq,
    const float* __restrict__ An2, const float* __restrict__ Bn2,
    float* __restrict__ out) {
  __shared__ char smem[WRITE ? 103424 : 159744];
  constexpr int ROFF = WRITE ? ROFF1 : ROFF0;
  constexpr int NXB = WRITE ? 2 : 4;   // X' buffers
  constexpr int NRB = WRITE ? 2 : 4;   // raw buffers
  constexpr int NB  = WRITE ? NB1 : NB0;
  float* O = (float*)(smem + OOFF1);

  const int tid = threadIdx.x;
  const int lane = tid & 63;
  const int wv = tid >> 6;     // 0..7
  const int l15 = lane & 15;
  const int lg = lane >> 4;
  const int d0 = wv * 32;
  const int ch0 = wv * CH;
  const int fr0 = fsw(l15) << 4;        // read-side swizzle, rows l15 / 16+l15
  const int fr1 = fsw(16 + l15) << 4;

  // B fragments, register-resident: B[k=c][n=d] = Wt[d][c]
  s16x8 bfr[2][8];
#pragma unroll
  for (int nt = 0; nt < 2; ++nt)
#pragma unroll
    for (int kt = 0; kt < 8; ++kt)
      bfr[nt][kt] = *(const s16x8*)(Wt + (d0 + nt * 16 + l15) * 256 + kt * 32 + lg * 8);

  // formation table, register-resident (n-invariant)
  u32x4 tbr[NS];
#pragma unroll
  for (int s = 0; s < NS; ++s)
    if (s * 64 + lane < CH) tbr[s] = *(const u32x4*)(tab + 4 * (ch0 + s * 64 + lane));

  // BN affine tables, register-resident (n-invariant), WRITE only
  f32x4 anr[NS], bnr[NS];
  if (WRITE) {
#pragma unroll
    for (int s = 0; s < NS; ++s)
      if (s * 64 + lane < CH) {
        anr[s] = *(const f32x4*)(An2 + 4 * (ch0 + s * 64 + lane));
        bnr[s] = *(const f32x4*)(Bn2 + 4 * (ch0 + s * 64 + lane));
      }
  }

  // zero pad rows 23..31 of all X' buffers (never written again)
  for (int i = tid; i < NXB * 1152; i += 512) {
    int b = i / 1152;
    *(int*)(smem + b * 16384 + 11776 + (i - b * 1152) * 4) = 0;
  }

  float s1[2][2][4], s2[2][2][4];
  if (!WRITE) {
#pragma unroll
    for (int mt = 0; mt < 2; ++mt)
#pragma unroll
      for (int nt = 0; nt < 2; ++nt)
#pragma unroll
        for (int r = 0; r < 4; ++r) { s1[mt][nt][r] = 0.f; s2[mt][nt][r] = 0.f; }
  }

  const int nbase = blockIdx.x * NB;
  // pass 2 runs its window in reverse: pass 1 left the tail L3-resident
  auto nmap = [&](int T) { return nbase + (WRITE ? (NB - 1 - T) : T); };

  f32x4 xres[2][NS];  // WRITE: residual slabs stashed at form time (parity slots)

  auto stage = [&](int T) {  // 23 exact DMAs for slab T -> raw[T%NRB]
    if (T >= NB) return;
    const char* gs = (const char*)(x0 + (size_t)nmap(T) * FLAT);
    char* lb = smem + ROFF + (T % NRB) * SLAB;
    gl_lds16(gs + (wv << 10) + lane * 16, lb + (wv << 10));
    gl_lds16(gs + ((8 + wv) << 10) + lane * 16, lb + ((8 + wv) << 10));
    if (wv < 7)
      gl_lds16(gs + ((16 + wv) << 10) + lane * 16, lb + ((16 + wv) << 10));
  };
  auto form = [&](int T, auto SL) {  // X' into Xb[T%NXB] from raw[T%NRB]; stash xres[SL]
    if (T >= NB) return;
    const char* rb = smem + ROFF + (T % NRB) * SLAB;
    char* xb = smem + (T % NXB) * 16384;
#pragma unroll
    for (int s = 0; s < NS; ++s)
      if (s * 64 + lane < CH) {
        f32x4 xv = *(const f32x4*)(rb + (ch0 + s * 64 + lane) * 16);
        if (WRITE) xres[SL.value][s] = xv;
        u32x4 tb = tbr[s];
#pragma unroll
        for (int e = 0; e < 4; ++e) {
          unsigned tt = tb[e];
          *(short*)(xb + (tt & 0xffffu)) =
              (short)f2bf(xv[e] * __uint_as_float(tt & 0xffff0000u));
        }
      }
  };
  auto mstep = [&](int T, f32x4 (*acc)[2]) {  // y = X'(T) * W
    const char* xb = smem + (T % NXB) * 16384;
#pragma unroll
    for (int kt = 0; kt < 8; ++kt) {
      s16x8 af[2];
      af[0] = *(const s16x8*)(xb + (l15 << 9) + ((kt * 64 + lg * 16) ^ fr0));
      af[1] = *(const s16x8*)(xb + ((16 + l15) << 9) + ((kt * 64 + lg * 16) ^ fr1));
#pragma unroll
      for (int mt = 0; mt < 2; ++mt)
#pragma unroll
        for (int nt = 0; nt < 2; ++nt)
          acc[mt][nt] = __builtin_amdgcn_mfma_f32_16x16x32_bf16(
              af[mt], bfr[nt][kt], acc[mt][nt], 0, 0, 0);
    }
  };
  auto sstep = [&](f32x4 (*acc)[2]) {
#pragma unroll
    for (int mt = 0; mt < 2; ++mt)
#pragma unroll
      for (int nt = 0; nt < 2; ++nt)
#pragma unroll
        for (int r = 0; r < 4; ++r) {
          float y = acc[mt][nt][r];
          s1[mt][nt][r] += y;
          s2[mt][nt][r] += y * y;
        }
  };
  auto bar = []() {  // LDS-drain barrier: does NOT drain vmcnt
    asm volatile("s_waitcnt lgkmcnt(0)" ::: "memory");
    __builtin_amdgcn_s_barrier();
    asm volatile("" ::: "memory");
  };

  if (!WRITE) {
    // ---------------- stats pass: 2 slabs per phase ----------------
    stage(0); stage(1); stage(2); stage(3);
    asm volatile("s_waitcnt vmcnt(0)" ::: "memory");
    bar();
    form(0, Ic<0>{}); form(1, Ic<0>{});
    for (int u = 0; u < NB0 / 2; ++u) {
      int t = 2 * u;
      asm volatile("s_waitcnt vmcnt(0)" ::: "memory");  // prev phase's stages done
      bar();  // all waves' DMAs + forms visible; prev readers done
      stage(t + 4); stage(t + 5);
      f32x4 acc[2][2];
      __builtin_amdgcn_s_setprio(1);
#pragma unroll
      for (int mt = 0; mt < 2; ++mt)
#pragma unroll
        for (int nt = 0; nt < 2; ++nt) acc[mt][nt] = (f32x4){0.f, 0.f, 0.f, 0.f};
      mstep(t, acc);
      sstep(acc);
#pragma unroll
      for (int mt = 0; mt < 2; ++mt)
#pragma unroll
        for (int nt = 0; nt < 2; ++nt) acc[mt][nt] = (f32x4){0.f, 0.f, 0.f, 0.f};
      mstep(t + 1, acc);
      __builtin_amdgcn_s_setprio(0);
      sstep(acc);
      form(t + 2, Ic<0>{}); form(t + 3, Ic<0>{});
    }
#pragma unroll
    for (int mt = 0; mt < 2; ++mt)
#pragma unroll
      for (int nt = 0; nt < 2; ++nt)
#pragma unroll
        for (int r = 0; r < 4; ++r) {
          int w = mt * 16 + lg * 4 + r;
          if (w < NV) {
            int d = d0 + nt * 16 + l15;
            atomicAdd(sum + (w << 8) + d, s1[mt][nt][r]);
            atomicAdd(ssq + (w << 8) + d, s2[mt][nt][r]);
          }
        }
    return;
  }

  // ---------------- output pass: 1 slab per phase ----------------
  stage(0); stage(1);
  asm volatile("s_waitcnt vmcnt(0)" ::: "memory");
  bar();
  form(0, Ic<0>{});

  auto wphase = [&](auto PP, int t) {  // slab t; PP = t&1 (compile-time xres slot)
    constexpr int P = PP.value;
    // prev phase's 3 DMAs must land (oldest); 3 NT stores may linger (newest)
    if (t) asm volatile("s_waitcnt vmcnt(3)" ::: "memory");
    else   asm volatile("s_waitcnt vmcnt(0)" ::: "memory");
    bar();  // all waves' DMA(t+1) + form(t) visible; prev X'/O readers done
    stage(t + 2);

    f32x4 acc[2][2];
#pragma unroll
    for (int mt = 0; mt < 2; ++mt)
#pragma unroll
      for (int nt = 0; nt < 2; ++nt) acc[mt][nt] = (f32x4){0.f, 0.f, 0.f, 0.f};
    __builtin_amdgcn_s_setprio(1);
    mstep(t, acc);
    __builtin_amdgcn_s_setprio(0);

    // scatter y -> O at out-shifted j = d*23 + (w+d)%23 (wave-local region)
#pragma unroll
    for (int mt = 0; mt < 2; ++mt)
#pragma unroll
      for (int nt = 0; nt < 2; ++nt)
#pragma unroll
        for (int r = 0; r < 4; ++r) {
          int w = mt * 16 + lg * 4 + r;  // C/D: row = (lane>>4)*4 + reg
          if (w < NV) {
            int d = d0 + nt * 16 + l15;  // col = lane & 15
            int sj = w + d; sj -= NV * divNV(sj);
            O[d * NV + sj] = acc[mt][nt][r];
          }
        }
    // same-wave readback: normalize + residual (xres regs) + relu, NT store
    float* og = out + (size_t)nmap(t) * FLAT;
#pragma unroll
    for (int s = 0; s < NS; ++s)
      if (s * 64 + lane < CH) {
        int i = ch0 + s * 64 + lane;
        f32x4 y = *(const f32x4*)(O + 4 * i);
        f32x4 o;
#pragma unroll
        for (int e = 0; e < 4; ++e)
          o[e] = fmaxf(fmaf(y[e], anr[s][e], bnr[s][e]) + xres[P][s][e], 0.0f);
        __builtin_nontemporal_store(o, (f32x4*)og + i);
      }
    // form next slab last: writes drain into the next barrier
    form(t + 1, Ic<P ^ 1>{});
  };

  for (int t = 0; t < NB1; t += 2) {
    wphase(Ic<0>{}, t);
    wphase(Ic<1>{}, t + 1);
  }
}

extern "C" void kernel_launch(void* const* d_in, const int* in_sizes, int n_in,
                              void* d_out, int out_size, void* d_ws, size_t ws_size,
                              hipStream_t stream) {
  const float* x0   = (const float*)d_in[0];
  const float* W    = (const float*)d_in[1];
  // d_in[2] = bias: cancels inside BN -> unused
  const float* mask = (const float*)d_in[3];
  const float* bnw  = (const float*)d_in[4];
  const float* bnb  = (const float*)d_in[5];
  // d_in[6], d_in[7] = shift tables: folded into addressing
  float* out = (float*)d_out;

  char* ws = (char*)d_ws;
  short* Wt     = (short*)ws;
  unsigned* tab = (unsigned*)(ws + 131072);
  float* sum    = (float*)(ws + 154624);
  float* ssq    = (float*)(ws + 178176);
  float* An2    = (float*)(ws + 201728);
  float* Bn2    = (float*)(ws + 225280);

  k_prep<<<256, 256, 0, stream>>>(W, mask, Wt, tab, sum);
  k_gemm<0><<<512, 512, 0, stream>>>(x0, Wt, tab, sum, ssq, nullptr, nullptr, nullptr);
  k_finalize<<<23, 256, 0, stream>>>(sum, ssq, bnw, bnb, An2, Bn2);
  k_gemm<1><<<512, 512, 0, stream>>>(x0, Wt, tab, sum, ssq, An2, Bn2, out);
}